// Round 1
// baseline (172.030 us; speedup 1.0000x reference)
//
#include <hip/hip_runtime.h>

constexpr int   ND_  = 16;
constexpr int   C_   = 512;
constexpr float EPS_ = 1e-5f;

// ---------------- Kernel 1: per-chunk partial stats -----------------------
// grid = (2, NCHUNK); block = 128. Block (bx, by) handles channels
// [bx*256, bx*256+256) of rows [by*256, by*256+256), accumulating per-domain
// sum / sumsq in LDS, then dumps partials to global (d_out used as scratch).
__global__ __launch_bounds__(128) void k_stats(
    const float2* __restrict__ X2, const int* __restrict__ dd,
    float* __restrict__ part_sum, float* __restrict__ part_sq,
    int* __restrict__ pcnt, int rows_per_chunk, int N) {
  __shared__ float2 ssum[ND_][128];
  __shared__ float2 ssq [ND_][128];
  __shared__ int    sd[512];        // domain id per row of this chunk
  __shared__ int    scnt[ND_];

  const int tid = threadIdx.x;
  const int bx  = blockIdx.x;       // channel half: 0 or 1
  const int by  = blockIdx.y;       // row chunk

  for (int i = tid; i < ND_ * 128; i += 128) {
    ((float2*)ssum)[i] = make_float2(0.f, 0.f);
    ((float2*)ssq )[i] = make_float2(0.f, 0.f);
  }
  if (tid < ND_) scnt[tid] = 0;
  __syncthreads();

  const int r0 = by * rows_per_chunk;
  const int r1 = min(N, r0 + rows_per_chunk);
  const int nr = r1 - r0;

  for (int i = tid; i < nr; i += 128) {
    const int v = dd[r0 + i];
    sd[i] = v;
    if (bx == 0) atomicAdd(&scnt[v], 1);
  }
  __syncthreads();

  const int ch2 = bx * 128 + tid;   // float2 column index (row = 256 float2)
  #pragma unroll 4
  for (int j = 0; j < nr; ++j) {
    const int    dn = sd[j];        // wave-uniform
    const float2 v  = X2[(size_t)(r0 + j) * (C_ / 2) + ch2];
    float2 a = ssum[dn][tid];
    a.x += v.x; a.y += v.y;
    ssum[dn][tid] = a;
    float2 b = ssq[dn][tid];
    b.x = fmaf(v.x, v.x, b.x);
    b.y = fmaf(v.y, v.y, b.y);
    ssq[dn][tid] = b;
  }
  __syncthreads();

  float2* ps = (float2*)part_sum;
  float2* pq = (float2*)part_sq;
  const size_t base = (size_t)by * ND_ * (C_ / 2);
  #pragma unroll
  for (int dom = 0; dom < ND_; ++dom) {
    ps[base + dom * (C_ / 2) + ch2] = ssum[dom][tid];
    pq[base + dom * (C_ / 2) + ch2] = ssq [dom][tid];
  }
  if (bx == 0 && tid < ND_) pcnt[by * ND_ + tid] = scnt[tid];
}

// ---------------- Kernel 2: reduce partials -> scale/shift ----------------
// grid = 32 blocks * 256 threads = 8192 = 16 domains * 512 channels.
__global__ __launch_bounds__(256) void k_finalize(
    const float* __restrict__ part_sum, const float* __restrict__ part_sq,
    const int* __restrict__ pcnt, const float* __restrict__ gamma,
    const float* __restrict__ beta, float* __restrict__ scale,
    float* __restrict__ shift, int nchunk) {
  const int gid = blockIdx.x * 256 + threadIdx.x;   // [0, 16*512)
  const int dom = gid >> 9;
  const int c   = gid & (C_ - 1);
  float s = 0.f, q = 0.f;
  for (int ch = 0; ch < nchunk; ++ch) {
    const size_t o = ((size_t)ch * ND_ + dom) * C_ + c;
    s += part_sum[o];
    q += part_sq[o];
  }
  int cnt = 0;
  for (int ch = 0; ch < nchunk; ++ch) cnt += pcnt[ch * ND_ + dom];
  const float fc   = fmaxf((float)cnt, 1.f);
  const float mean = s / fc;
  const float var  = q / fc - mean * mean;
  const float inv  = rsqrtf(var + EPS_);
  const float sc   = inv * gamma[gid];
  scale[gid] = sc;
  shift[gid] = fmaf(-mean, sc, beta[gid]);
}

// ---------------- Kernel 3: normalize ------------------------------------
// Grid-stride over float4 elements; y = fma(x, scale[d][c], shift[d][c]).
__global__ __launch_bounds__(256) void k_norm(
    const float4* __restrict__ X4, const int* __restrict__ dd,
    const float4* __restrict__ scale4, const float4* __restrict__ shift4,
    float4* __restrict__ Y4, int total4) {
  int i = blockIdx.x * 256 + threadIdx.x;
  const int stride = gridDim.x * 256;
  for (; i < total4; i += stride) {
    const int n  = i >> 7;          // C/4 = 128 float4 per row
    const int c4 = i & 127;
    const int dn = dd[n];           // wave-uniform (128 float4 per row)
    const float4 x  = X4[i];
    const float4 sc = scale4[dn * (C_ / 4) + c4];
    const float4 sh = shift4[dn * (C_ / 4) + c4];
    float4 y;
    y.x = fmaf(x.x, sc.x, sh.x);
    y.y = fmaf(x.y, sc.y, sh.y);
    y.z = fmaf(x.z, sc.z, sh.z);
    y.w = fmaf(x.w, sc.w, sh.w);
    Y4[i] = y;
  }
}

extern "C" void kernel_launch(void* const* d_in, const int* in_sizes, int n_in,
                              void* d_out, int out_size, void* d_ws, size_t ws_size,
                              hipStream_t stream) {
  const float* X     = (const float*)d_in[0];
  const int*   dd    = (const int*)  d_in[1];
  // d_in[2] = parameter_t, d_in[3] = fm_mean : unused by the reference math
  const float* gamma = (const float*)d_in[4];
  const float* beta  = (const float*)d_in[5];
  float*       out   = (float*)d_out;

  const int N      = in_sizes[1];             // 65536
  const int rpc    = 256;                     // rows per chunk
  const int NCHUNK = (N + rpc - 1) / rpc;     // 256

  // Partials live in d_out (scratch until k_norm overwrites it):
  //   part_sum[NCHUNK][16][512], part_sq[NCHUNK][16][512], pcnt[NCHUNK][16]
  float* part_sum = out;
  float* part_sq  = out + (size_t)NCHUNK * ND_ * C_;
  int*   pcnt     = (int*)(part_sq + (size_t)NCHUNK * ND_ * C_);
  // scale/shift must survive k_norm -> keep in d_ws (64 KB).
  float* scale = (float*)d_ws;
  float* shift = scale + ND_ * C_;

  dim3 g1(2, NCHUNK);
  k_stats<<<g1, 128, 0, stream>>>((const float2*)X, dd, part_sum, part_sq,
                                  pcnt, rpc, N);
  k_finalize<<<(ND_ * C_) / 256, 256, 0, stream>>>(
      part_sum, part_sq, pcnt, gamma, beta, scale, shift, NCHUNK);

  const int total4 = N * (C_ / 4);
  int blocks = (total4 + 255) / 256;
  if (blocks > 2048) blocks = 2048;
  k_norm<<<blocks, 256, 0, stream>>>((const float4*)X, dd,
                                     (const float4*)scale,
                                     (const float4*)shift,
                                     (float4*)out, total4);
}

// Round 2
// 93.006 us; speedup vs baseline: 1.8497x; 1.8497x over previous
//
#include <hip/hip_runtime.h>

constexpr int   ND_  = 16;
constexpr int   C_   = 512;
constexpr float EPS_ = 1e-5f;

// ---------------- Kernel 1: per-chunk partial stats -----------------------
// grid = (2, NCHUNK); block = 128. Block (bx, by) handles channels
// [bx*256, bx*256+256) of rows [by*256, by*256+256), accumulating per-domain
// sum / sumsq in LDS, then dumps partials to global (d_out used as scratch).
__global__ __launch_bounds__(128) void k_stats(
    const float2* __restrict__ X2, const int* __restrict__ dd,
    float* __restrict__ part_sum, float* __restrict__ part_sq,
    int* __restrict__ pcnt, int rows_per_chunk, int N) {
  __shared__ float2 ssum[ND_][128];
  __shared__ float2 ssq [ND_][128];
  __shared__ int    sd[512];        // domain id per row of this chunk
  __shared__ int    scnt[ND_];

  const int tid = threadIdx.x;
  const int bx  = blockIdx.x;       // channel half: 0 or 1
  const int by  = blockIdx.y;       // row chunk

  for (int i = tid; i < ND_ * 128; i += 128) {
    ((float2*)ssum)[i] = make_float2(0.f, 0.f);
    ((float2*)ssq )[i] = make_float2(0.f, 0.f);
  }
  if (tid < ND_) scnt[tid] = 0;
  __syncthreads();

  const int r0 = by * rows_per_chunk;
  const int r1 = min(N, r0 + rows_per_chunk);
  const int nr = r1 - r0;

  for (int i = tid; i < nr; i += 128) {
    const int v = dd[r0 + i];
    sd[i] = v;
    if (bx == 0) atomicAdd(&scnt[v], 1);
  }
  __syncthreads();

  const int ch2 = bx * 128 + tid;   // float2 column index (row = 256 float2)
  #pragma unroll 4
  for (int j = 0; j < nr; ++j) {
    const int    dn = sd[j];        // wave-uniform
    const float2 v  = X2[(size_t)(r0 + j) * (C_ / 2) + ch2];
    float2 a = ssum[dn][tid];
    a.x += v.x; a.y += v.y;
    ssum[dn][tid] = a;
    float2 b = ssq[dn][tid];
    b.x = fmaf(v.x, v.x, b.x);
    b.y = fmaf(v.y, v.y, b.y);
    ssq[dn][tid] = b;
  }
  __syncthreads();

  float2* ps = (float2*)part_sum;
  float2* pq = (float2*)part_sq;
  const size_t base = (size_t)by * ND_ * (C_ / 2);
  #pragma unroll
  for (int dom = 0; dom < ND_; ++dom) {
    ps[base + dom * (C_ / 2) + ch2] = ssum[dom][tid];
    pq[base + dom * (C_ / 2) + ch2] = ssq [dom][tid];
  }
  if (bx == 0 && tid < ND_) pcnt[by * ND_ + tid] = scnt[tid];
}

// ---------------- Kernel 2: reduce partials -> scale/shift ----------------
// grid = (ND_*C_)/32 = 256 blocks x 256 threads. Each block owns 32
// consecutive outputs (gid = dom*512 + c; one domain per block since 32|512).
// Thread t: output lane (t&31), chunk-segment (t>>5) of 8; segment sums
// reduced via LDS. Fixes R1's 95us latency-bound serial chunk walk.
__global__ __launch_bounds__(256) void k_finalize(
    const float* __restrict__ part_sum, const float* __restrict__ part_sq,
    const int* __restrict__ pcnt, const float* __restrict__ gamma,
    const float* __restrict__ beta, float* __restrict__ scale,
    float* __restrict__ shift, int nchunk) {
  __shared__ float ssum[8][32];
  __shared__ float ssq [8][32];
  __shared__ int   scnt[8];

  const int t     = threadIdx.x;
  const int lane  = t & 31;          // output within block
  const int seg   = t >> 5;          // chunk segment 0..7
  const int out0  = blockIdx.x * 32;
  const int gid   = out0 + lane;     // dom*512 + c
  const int dom   = out0 >> 9;       // uniform across block
  const int c     = gid & (C_ - 1);
  const int cpl   = (nchunk + 7) / 8;

  float s = 0.f, q = 0.f;
  int   cn = 0;
  for (int k = 0; k < cpl; ++k) {
    const int ch = seg * cpl + k;
    if (ch < nchunk) {
      const size_t o = ((size_t)ch * ND_ + dom) * C_ + c;
      s += part_sum[o];
      q += part_sq[o];
      cn += pcnt[ch * ND_ + dom];
    }
  }
  ssum[seg][lane] = s;
  ssq [seg][lane] = q;
  if (lane == 0) scnt[seg] = cn;
  __syncthreads();

  if (t < 32) {
    float S = 0.f, Q = 0.f;
    #pragma unroll
    for (int sg = 0; sg < 8; ++sg) { S += ssum[sg][t]; Q += ssq[sg][t]; }
    int CN = 0;
    #pragma unroll
    for (int sg = 0; sg < 8; ++sg) CN += scnt[sg];
    const float fc   = fmaxf((float)CN, 1.f);
    const float mean = S / fc;
    const float var  = Q / fc - mean * mean;
    const float inv  = rsqrtf(var + EPS_);
    const int   g    = out0 + t;
    const float sc   = inv * gamma[g];
    scale[g] = sc;
    shift[g] = fmaf(-mean, sc, beta[g]);
  }
}

// ---------------- Kernel 3: normalize ------------------------------------
// Grid-stride over float4 elements; y = fma(x, scale[d][c], shift[d][c]).
__global__ __launch_bounds__(256) void k_norm(
    const float4* __restrict__ X4, const int* __restrict__ dd,
    const float4* __restrict__ scale4, const float4* __restrict__ shift4,
    float4* __restrict__ Y4, int total4) {
  int i = blockIdx.x * 256 + threadIdx.x;
  const int stride = gridDim.x * 256;
  for (; i < total4; i += stride) {
    const int n  = i >> 7;          // C/4 = 128 float4 per row
    const int c4 = i & 127;
    const int dn = dd[n];           // wave-uniform (128 float4 per row)
    const float4 x  = X4[i];
    const float4 sc = scale4[dn * (C_ / 4) + c4];
    const float4 sh = shift4[dn * (C_ / 4) + c4];
    float4 y;
    y.x = fmaf(x.x, sc.x, sh.x);
    y.y = fmaf(x.y, sc.y, sh.y);
    y.z = fmaf(x.z, sc.z, sh.z);
    y.w = fmaf(x.w, sc.w, sh.w);
    Y4[i] = y;
  }
}

extern "C" void kernel_launch(void* const* d_in, const int* in_sizes, int n_in,
                              void* d_out, int out_size, void* d_ws, size_t ws_size,
                              hipStream_t stream) {
  const float* X     = (const float*)d_in[0];
  const int*   dd    = (const int*)  d_in[1];
  // d_in[2] = parameter_t, d_in[3] = fm_mean : unused by the reference math
  const float* gamma = (const float*)d_in[4];
  const float* beta  = (const float*)d_in[5];
  float*       out   = (float*)d_out;

  const int N      = in_sizes[1];             // 65536
  const int rpc    = 256;                     // rows per chunk
  const int NCHUNK = (N + rpc - 1) / rpc;     // 256

  // Partials live in d_out (scratch until k_norm overwrites it):
  //   part_sum[NCHUNK][16][512], part_sq[NCHUNK][16][512], pcnt[NCHUNK][16]
  float* part_sum = out;
  float* part_sq  = out + (size_t)NCHUNK * ND_ * C_;
  int*   pcnt     = (int*)(part_sq + (size_t)NCHUNK * ND_ * C_);
  // scale/shift must survive k_norm -> keep in d_ws (64 KB).
  float* scale = (float*)d_ws;
  float* shift = scale + ND_ * C_;

  dim3 g1(2, NCHUNK);
  k_stats<<<g1, 128, 0, stream>>>((const float2*)X, dd, part_sum, part_sq,
                                  pcnt, rpc, N);
  k_finalize<<<(ND_ * C_) / 32, 256, 0, stream>>>(
      part_sum, part_sq, pcnt, gamma, beta, scale, shift, NCHUNK);

  const int total4 = N * (C_ / 4);
  int blocks = (total4 + 255) / 256;
  if (blocks > 2048) blocks = 2048;
  k_norm<<<blocks, 256, 0, stream>>>((const float4*)X, dd,
                                     (const float4*)scale,
                                     (const float4*)shift,
                                     (float4*)out, total4);
}

// Round 3
// 84.523 us; speedup vs baseline: 2.0353x; 1.1004x over previous
//
#include <hip/hip_runtime.h>

constexpr int   ND_  = 16;
constexpr int   C_   = 512;
constexpr float EPS_ = 1e-5f;

// ---------------- Kernel 1: per-chunk partial stats -----------------------
// grid = (2, NCHUNK); block = 256 = 2 row-groups x 128 channel-lanes(float2).
// Block (bx, by): channels [bx*256, +256) of rows [by*256, +256); row-group g
// handles rows [by*256 + g*128, +128) into its OWN LDS accumulators (no
// cross-wave RMW races), merged before the partial dump. 66 KB LDS -> 2
// blocks/CU -> 8 waves/CU (R2 had 4: load pipe starved at ~900cy HBM lat).
__global__ __launch_bounds__(256) void k_stats(
    const float2* __restrict__ X2, const int* __restrict__ dd,
    float* __restrict__ part_sum, float* __restrict__ part_sq,
    int* __restrict__ pcnt, int rows_per_chunk, int N) {
  __shared__ float2 ssum[2][ND_][128];
  __shared__ float2 ssq [2][ND_][128];
  __shared__ int    sd[256];        // domain id per row of this chunk
  __shared__ int    scnt[ND_];

  const int tid  = threadIdx.x;
  const int g    = tid >> 7;        // row-group 0/1
  const int lane = tid & 127;       // channel lane (float2)
  const int bx   = blockIdx.x;      // channel half: 0 or 1
  const int by   = blockIdx.y;      // row chunk

  for (int i = tid; i < 2 * ND_ * 128; i += 256) {
    ((float2*)ssum)[i] = make_float2(0.f, 0.f);
    ((float2*)ssq )[i] = make_float2(0.f, 0.f);
  }
  if (tid < ND_) scnt[tid] = 0;
  __syncthreads();

  const int r0 = by * rows_per_chunk;
  const int r1 = min(N, r0 + rows_per_chunk);
  const int nr = r1 - r0;

  for (int i = tid; i < nr; i += 256) {
    const int v = dd[r0 + i];
    sd[i] = v;
    if (bx == 0) atomicAdd(&scnt[v], 1);
  }
  __syncthreads();

  // row-group g: rows [g*128, min(nr, g*128+128))
  const int jr0 = g * 128;
  const int jr1 = min(nr, jr0 + 128);
  const int ch2 = bx * 128 + lane;  // float2 column index (row = 256 float2)
  #pragma unroll 8
  for (int j = jr0; j < jr1; ++j) {
    const int    dn = sd[j];        // wave-uniform
    const float2 v  = X2[(size_t)(r0 + j) * (C_ / 2) + ch2];
    float2 a = ssum[g][dn][lane];
    a.x += v.x; a.y += v.y;
    ssum[g][dn][lane] = a;
    float2 b = ssq[g][dn][lane];
    b.x = fmaf(v.x, v.x, b.x);
    b.y = fmaf(v.y, v.y, b.y);
    ssq[g][dn][lane] = b;
  }
  __syncthreads();

  // merge row-group 1 into 0 (threads 0..127, one lane each)
  if (tid < 128) {
    #pragma unroll
    for (int dom = 0; dom < ND_; ++dom) {
      float2 a = ssum[0][dom][tid], a1 = ssum[1][dom][tid];
      a.x += a1.x; a.y += a1.y;
      ssum[0][dom][tid] = a;
      float2 b = ssq[0][dom][tid], b1 = ssq[1][dom][tid];
      b.x += b1.x; b.y += b1.y;
      ssq[0][dom][tid] = b;
    }
  }
  __syncthreads();

  float2* ps = (float2*)part_sum;
  float2* pq = (float2*)part_sq;
  const size_t base = (size_t)by * ND_ * (C_ / 2);
  for (int idx = tid; idx < ND_ * 128; idx += 256) {
    const int dom = idx >> 7;
    const int ln  = idx & 127;
    const size_t o = base + dom * (C_ / 2) + bx * 128 + ln;
    ps[o] = ssum[0][dom][ln];
    pq[o] = ssq [0][dom][ln];
  }
  if (bx == 0 && tid < ND_) pcnt[by * ND_ + tid] = scnt[tid];
}

// ---------------- Kernel 2: reduce partials -> scale/shift ----------------
// grid = (ND_*C_)/32 = 256 blocks x 256 threads. Each block owns 32
// consecutive outputs (gid = dom*512 + c; one domain per block since 32|512).
__global__ __launch_bounds__(256) void k_finalize(
    const float* __restrict__ part_sum, const float* __restrict__ part_sq,
    const int* __restrict__ pcnt, const float* __restrict__ gamma,
    const float* __restrict__ beta, float* __restrict__ scale,
    float* __restrict__ shift, int nchunk) {
  __shared__ float ssum[8][32];
  __shared__ float ssq [8][32];
  __shared__ int   scnt[8];

  const int t     = threadIdx.x;
  const int lane  = t & 31;          // output within block
  const int seg   = t >> 5;          // chunk segment 0..7
  const int out0  = blockIdx.x * 32;
  const int gid   = out0 + lane;     // dom*512 + c
  const int dom   = out0 >> 9;       // uniform across block
  const int c     = gid & (C_ - 1);
  const int cpl   = (nchunk + 7) / 8;

  float s = 0.f, q = 0.f;
  int   cn = 0;
  for (int k = 0; k < cpl; ++k) {
    const int ch = seg * cpl + k;
    if (ch < nchunk) {
      const size_t o = ((size_t)ch * ND_ + dom) * C_ + c;
      s += part_sum[o];
      q += part_sq[o];
      cn += pcnt[ch * ND_ + dom];
    }
  }
  ssum[seg][lane] = s;
  ssq [seg][lane] = q;
  if (lane == 0) scnt[seg] = cn;
  __syncthreads();

  if (t < 32) {
    float S = 0.f, Q = 0.f;
    #pragma unroll
    for (int sg = 0; sg < 8; ++sg) { S += ssum[sg][t]; Q += ssq[sg][t]; }
    int CN = 0;
    #pragma unroll
    for (int sg = 0; sg < 8; ++sg) CN += scnt[sg];
    const float fc   = fmaxf((float)CN, 1.f);
    const float mean = S / fc;
    const float var  = Q / fc - mean * mean;
    const float inv  = rsqrtf(var + EPS_);
    const int   g    = out0 + t;
    const float sc   = inv * gamma[g];
    scale[g] = sc;
    shift[g] = fmaf(-mean, sc, beta[g]);
  }
}

// ---------------- Kernel 3: normalize ------------------------------------
// Grid-stride over float4 elements; y = fma(x, scale[d][c], shift[d][c]).
__global__ __launch_bounds__(256) void k_norm(
    const float4* __restrict__ X4, const int* __restrict__ dd,
    const float4* __restrict__ scale4, const float4* __restrict__ shift4,
    float4* __restrict__ Y4, int total4) {
  int i = blockIdx.x * 256 + threadIdx.x;
  const int stride = gridDim.x * 256;
  for (; i < total4; i += stride) {
    const int n  = i >> 7;          // C/4 = 128 float4 per row
    const int c4 = i & 127;
    const int dn = dd[n];           // wave-uniform (128 float4 per row)
    const float4 x  = X4[i];
    const float4 sc = scale4[dn * (C_ / 4) + c4];
    const float4 sh = shift4[dn * (C_ / 4) + c4];
    float4 y;
    y.x = fmaf(x.x, sc.x, sh.x);
    y.y = fmaf(x.y, sc.y, sh.y);
    y.z = fmaf(x.z, sc.z, sh.z);
    y.w = fmaf(x.w, sc.w, sh.w);
    Y4[i] = y;
  }
}

extern "C" void kernel_launch(void* const* d_in, const int* in_sizes, int n_in,
                              void* d_out, int out_size, void* d_ws, size_t ws_size,
                              hipStream_t stream) {
  const float* X     = (const float*)d_in[0];
  const int*   dd    = (const int*)  d_in[1];
  // d_in[2] = parameter_t, d_in[3] = fm_mean : unused by the reference math
  const float* gamma = (const float*)d_in[4];
  const float* beta  = (const float*)d_in[5];
  float*       out   = (float*)d_out;

  const int N      = in_sizes[1];             // 65536
  const int rpc    = 256;                     // rows per chunk
  const int NCHUNK = (N + rpc - 1) / rpc;     // 256

  // Partials live in d_out (scratch until k_norm overwrites it):
  //   part_sum[NCHUNK][16][512], part_sq[NCHUNK][16][512], pcnt[NCHUNK][16]
  float* part_sum = out;
  float* part_sq  = out + (size_t)NCHUNK * ND_ * C_;
  int*   pcnt     = (int*)(part_sq + (size_t)NCHUNK * ND_ * C_);
  // scale/shift must survive k_norm -> keep in d_ws (64 KB).
  float* scale = (float*)d_ws;
  float* shift = scale + ND_ * C_;

  dim3 g1(2, NCHUNK);
  k_stats<<<g1, 256, 0, stream>>>((const float2*)X, dd, part_sum, part_sq,
                                  pcnt, rpc, N);
  k_finalize<<<(ND_ * C_) / 32, 256, 0, stream>>>(
      part_sum, part_sq, pcnt, gamma, beta, scale, shift, NCHUNK);

  const int total4 = N * (C_ / 4);
  int blocks = (total4 + 255) / 256;
  if (blocks > 2048) blocks = 2048;
  k_norm<<<blocks, 256, 0, stream>>>((const float4*)X, dd,
                                     (const float4*)scale,
                                     (const float4*)shift,
                                     (float4*)out, total4);
}